// Round 9
// baseline (132.637 us; speedup 1.0000x reference)
//
#include <hip/hip_runtime.h>
#include <hip/hip_bf16.h>

typedef __bf16 bf16x8 __attribute__((ext_vector_type(8)));
typedef __bf16 bf16x4 __attribute__((ext_vector_type(4)));
typedef float  f32x4  __attribute__((ext_vector_type(4)));

static constexpr int B = 2, S = 2048, D = 1024, H = 16, DK = 64;
static constexpr int M = B * S;          // 4096
static constexpr int NE = M * D;         // 4194304
static constexpr int WE = D * D;         // 1048576

__device__ inline float fast_exp2(float x) { return __builtin_amdgcn_exp2f(x); }

__device__ inline void gload16(const void* g, void* l) {
  __builtin_amdgcn_global_load_lds(
      (const __attribute__((address_space(1))) void*)g,
      (__attribute__((address_space(3))) void*)l, 16, 0, 0);
}

// zero-shuffle V permutation: store kv-inner i (i=32kc+16a+4lg+r) at lg*16+kc*8+a*4+r
__device__ inline int perm64(int i) {
  return (((i >> 2) & 3) << 4) | (((i >> 5) & 1) << 3) | (((i >> 4) & 1) << 2) | (i & 3);
}

// ---------------- f32 -> bf16 conversion: weights only ---------------------
__global__ __launch_bounds__(256) void cvt_w(
    const float* __restrict__ Wq, const float* __restrict__ Wk,
    const float* __restrict__ Wv, const float* __restrict__ Wo,
    __bf16* __restrict__ Wall)
{
  int z = blockIdx.y;
  const float* src = (z == 0) ? Wq : (z == 1) ? Wk : (z == 2) ? Wv : Wo;
  __bf16* dst = Wall + (size_t)z * WE;
  int n4 = WE / 4;
  int i = blockIdx.x * blockDim.x + threadIdx.x;
  int stride = gridDim.x * blockDim.x;
  for (; i < n4; i += stride) {
    float4 f = reinterpret_cast<const float4*>(src)[i];
    bf16x4 o;
    o[0] = (__bf16)f.x; o[1] = (__bf16)f.y; o[2] = (__bf16)f.z; o[3] = (__bf16)f.w;
    reinterpret_cast<bf16x4*>(dst)[i] = o;
  }
}

// ---------------- fused QKV projection, BK=64, swizzled LDS ----------------
// Swapped operands: acc = mfma(W-frag, X-frag). W via global_load_lds with
// pre-swizzled source (rule #21); X via coalesced f32 load + in-reg cvt +
// swizzled ds_write_b128. XCD-clustered 1D grid: W tiles L2-resident.
// Q pre-scaled by 0.125*log2(e); V stored transposed with perm64'd s-inner.
__global__ __launch_bounds__(256, 4) void proj_kernel(
    const float* __restrict__ Xq32, const float* __restrict__ Xk32,
    const float* __restrict__ Xv32, const __bf16* __restrict__ Wall,
    const float* __restrict__ bq_, const float* __restrict__ bk_,
    const float* __restrict__ bv_,
    const float* __restrict__ sinp, const float* __restrict__ cosp,
    __bf16* __restrict__ Qr, __bf16* __restrict__ Kr, __bf16* __restrict__ Vt)
{
  __shared__ __align__(16) __bf16 Ws[128 * 64];   // 16KB, swizzled rows (128B)
  __shared__ __align__(16) __bf16 Xs[128 * 64];   // 16KB, swizzled rows
  int tid = threadIdx.x;
  int lane = tid & 63, wid = tid >> 6;
  int lr = lane & 15, lg = lane >> 4;
  int wr = wid >> 1, wc = wid & 1;
  // XCD-clustered decode: per XCD, y hits only 3 W tiles (768KB, L2-fits)
  int L = blockIdx.x;
  int x = L / 24;
  int by = (L & 7) + 8 * ((L >> 3) % 3);
  int m0 = x * 128;
  int z  = by >> 3;                     // 0:Q 1:K 2:V
  const float*  X32  = (z == 0) ? Xq32 : (z == 1) ? Xk32 : Xv32;
  const __bf16* Bw   = Wall + (size_t)by * 128 * 1024;
  const float*  bias = (z == 0) ? bq_ : (z == 1) ? bk_ : bv_;

  // W staging: 4 chunks of 4KB; row = c*32 + (tid>>3); pre-swizzled source col
  int wrow = tid >> 3;                  // 0..31
  int wcol = 8 * ((tid & 7) ^ ((tid >> 3) & 7));   // swizzle-inverse source col
  char* wsbase = (char*)Ws + wid * 1024;

  // X staging: 4 passes; row = p*32 + (tid>>3); 2 f32x4 -> bf16x8 -> 1 b128
  int xrow = tid >> 3;
  int xcolf = (tid & 7) * 8;            // f32 col within BK=64
  int xwb = ((tid & 7) * 16) ^ (((tid >> 3) & 7) << 4);  // swizzled write byte

  f32x4 acc[4][4];
#pragma unroll
  for (int i = 0; i < 4; ++i)
#pragma unroll
    for (int j = 0; j < 4; ++j) acc[i][j] = (f32x4){0, 0, 0, 0};

  // frag read offsets (swizzled): row*128 + ((h*64 + lg*16) ^ ((lr&7)<<4))
  int fsw = (lr & 7) << 4;
  int foff0 = (lg * 16) ^ fsw;          // h=0
  int foff1 = (64 + lg * 16) ^ fsw;     // h=1

  // prologue: X prefetch for k0=0 (cvt at load time -> 4 bf16x8 = 16 VGPR)
  bf16x8 xb[4];
#pragma unroll
  for (int p = 0; p < 4; ++p) {
    const float* xp = X32 + (size_t)(m0 + p * 32 + xrow) * 1024 + xcolf;
    f32x4 a = *(const f32x4*)(xp);
    f32x4 b = *(const f32x4*)(xp + 4);
    bf16x8 v;
#pragma unroll
    for (int e = 0; e < 4; ++e) { v[e] = (__bf16)a[e]; v[4 + e] = (__bf16)b[e]; }
    xb[p] = v;
  }

  for (int k0 = 0; k0 < 1024; k0 += 64) {
    // W stage (4 x gload16, pre-swizzled source)
#pragma unroll
    for (int c = 0; c < 4; ++c)
      gload16(Bw + (size_t)(c * 32 + wrow) * 1024 + k0 + wcol,
              wsbase + c * 4096);
    // X stage: write prefetched bf16x8 (swizzled)
#pragma unroll
    for (int p = 0; p < 4; ++p)
      *(bf16x8*)((char*)Xs + (p * 32 + xrow) * 128 + xwb) = xb[p];
    __syncthreads();
    // prefetch next X (latency hides under MFMA)
    if (k0 + 64 < 1024) {
#pragma unroll
      for (int p = 0; p < 4; ++p) {
        const float* xp = X32 + (size_t)(m0 + p * 32 + xrow) * 1024 + k0 + 64 + xcolf;
        f32x4 a = *(const f32x4*)(xp);
        f32x4 b = *(const f32x4*)(xp + 4);
        bf16x8 v;
#pragma unroll
        for (int e = 0; e < 4; ++e) { v[e] = (__bf16)a[e]; v[4 + e] = (__bf16)b[e]; }
        xb[p] = v;
      }
    }
    // compute: two K-halves of 32, 16 MFMA each
#pragma unroll
    for (int h = 0; h < 2; ++h) {
      int fo = h ? foff1 : foff0;
      bf16x8 af[4], bfr[4];
#pragma unroll
      for (int mi = 0; mi < 4; ++mi)
        af[mi] = *(const bf16x8*)((char*)Ws + (wr * 64 + mi * 16 + lr) * 128 + fo);
#pragma unroll
      for (int ni = 0; ni < 4; ++ni)
        bfr[ni] = *(const bf16x8*)((char*)Xs + (wc * 64 + ni * 16 + lr) * 128 + fo);
#pragma unroll
      for (int mi = 0; mi < 4; ++mi)
#pragma unroll
        for (int ni = 0; ni < 4; ++ni)
          acc[mi][ni] = __builtin_amdgcn_mfma_f32_16x16x32_bf16(af[mi], bfr[ni], acc[mi][ni], 0, 0, 0);
    }
    __syncthreads();
  }

  // epilogue: D row = dkf = by*128 + wr*64 + mi*16 + lg*4 + i ; D col = s
#pragma unroll
  for (int mi = 0; mi < 4; ++mi) {
    int dkf0 = by * 128 + wr * 64 + mi * 16 + lg * 4;
    int col0 = dkf0 & 1023;
    int h = col0 >> 6, dk0 = col0 & 63, t0 = dk0 >> 1;
    float4 bv4 = *reinterpret_cast<const float4*>(&bias[col0]);
#pragma unroll
    for (int ni = 0; ni < 4; ++ni) {
      int r = m0 + wc * 64 + ni * 16 + lr;
      int s = r & (S - 1), bb = r >> 11;
      float v0 = acc[mi][ni][0] + bv4.x;
      float v1 = acc[mi][ni][1] + bv4.y;
      float v2 = acc[mi][ni][2] + bv4.z;
      float v3 = acc[mi][ni][3] + bv4.w;
      if (z < 2) {
        float2 sn = *reinterpret_cast<const float2*>(&sinp[s * 32 + t0]);
        float2 cs = *reinterpret_cast<const float2*>(&cosp[s * 32 + t0]);
        float e0 = v0 * cs.x - v1 * sn.x, o0 = v0 * sn.x + v1 * cs.x;
        float e1 = v2 * cs.y - v3 * sn.y, o1 = v2 * sn.y + v3 * cs.y;
        if (z == 0) {
          e0 *= 0.18033688011112042f; o0 *= 0.18033688011112042f;  // 0.125*log2(e)
          e1 *= 0.18033688011112042f; o1 *= 0.18033688011112042f;
        }
        bf16x4 w;
        w[0] = (__bf16)e0; w[1] = (__bf16)o0; w[2] = (__bf16)e1; w[3] = (__bf16)o1;
        __bf16* dst = (z == 0) ? Qr : Kr;
        *(bf16x4*)&dst[((size_t)(bb * H + h) * S + s) * DK + dk0] = w;
      } else {
        int sp = (s & ~63) | perm64(s & 63);
        size_t base = ((size_t)(bb * H + h) * DK + dk0) * S + sp;
        Vt[base]         = (__bf16)v0;
        Vt[base + S]     = (__bf16)v1;
        Vt[base + 2 * S] = (__bf16)v2;
        Vt[base + 3 * S] = (__bf16)v3;
      }
    }
  }
}

// ---------------- output projection: 64x128 tiles, 2 blocks/CU -------------
__global__ __launch_bounds__(256) void outproj_kernel(
    const __bf16* __restrict__ AO, const __bf16* __restrict__ Wo,
    const float* __restrict__ bo_, float* __restrict__ out)
{
  __shared__ __align__(16) __bf16 As[64 * 32];    // AO tile (4KB)
  __shared__ __align__(16) __bf16 Bs[128 * 32];   // Wo tile (8KB)
  int tid = threadIdx.x;
  int lane = tid & 63, wid = tid >> 6;
  int lr = lane & 15, lg = lane >> 4;
  int wr = wid >> 1, wc = wid & 1;
  // XCD-clustered: y = L&7 -> one Wo tile per XCD (256KB, L2-resident)
  int L = blockIdx.x;
  int n0 = (L & 7) * 128;
  int m0 = (L >> 3) * 64;

  int arow = tid >> 2;                  // 0..63
  int acol = (tid & 3) * 8;
  int brow = tid >> 2;
  int bcol = (tid & 3) * 8;
  char* asw = (char*)As + wid * 1024;
  char* bsw = (char*)Bs + wid * 1024;

  f32x4 acc[4][2];
#pragma unroll
  for (int i = 0; i < 4; ++i)
#pragma unroll
    for (int j = 0; j < 2; ++j) acc[i][j] = (f32x4){0, 0, 0, 0};

  for (int k0 = 0; k0 < 1024; k0 += 32) {
    gload16(AO + (size_t)(m0 + arow) * 1024 + k0 + acol, asw);
    gload16(Wo + (size_t)(n0 + brow) * 1024 + k0 + bcol, bsw);
    gload16(Wo + (size_t)(n0 + brow + 64) * 1024 + k0 + bcol, bsw + 4096);
    __syncthreads();
    bf16x8 wf[4], aof[2];
#pragma unroll
    for (int mi = 0; mi < 4; ++mi)
      wf[mi]  = *reinterpret_cast<const bf16x8*>(&Bs[(wr*64 + mi*16 + lr)*32 + lg*8]);
#pragma unroll
    for (int ni = 0; ni < 2; ++ni)
      aof[ni] = *reinterpret_cast<const bf16x8*>(&As[(wc*32 + ni*16 + lr)*32 + lg*8]);
#pragma unroll
    for (int mi = 0; mi < 4; ++mi)
#pragma unroll
      for (int ni = 0; ni < 2; ++ni)
        acc[mi][ni] = __builtin_amdgcn_mfma_f32_16x16x32_bf16(wf[mi], aof[ni], acc[mi][ni], 0, 0, 0);
    __syncthreads();
  }

#pragma unroll
  for (int mi = 0; mi < 4; ++mi) {
    int c0 = n0 + wr * 64 + mi * 16 + lg * 4;
    float4 bv4 = *reinterpret_cast<const float4*>(&bo_[c0]);
#pragma unroll
    for (int ni = 0; ni < 2; ++ni) {
      int r = m0 + wc * 32 + ni * 16 + lr;
      float4 w;
      w.x = acc[mi][ni][0] + bv4.x;
      w.y = acc[mi][ni][1] + bv4.y;
      w.z = acc[mi][ni][2] + bv4.z;
      w.w = acc[mi][ni][3] + bv4.w;
      *reinterpret_cast<float4*>(&out[(size_t)r * 1024 + c0]) = w;
    }
  }
}

// ---------------- flash attention: 4-warp block, LDS-shared K/V ------------
__global__ __launch_bounds__(256, 4) void attn_kernel(
    const __bf16* __restrict__ Qr, const __bf16* __restrict__ Kr,
    const __bf16* __restrict__ Vt, __bf16* __restrict__ AO)
{
  __shared__ __align__(16) char smem[32768];   // [2][ K 8KB | V 8KB ]
  int tid = threadIdx.x;
  int lane = tid & 63, wid = tid >> 6;
  int lr = lane & 15, lg = lane >> 4;
  int bx = blockIdx.x;
  int bh = (bx & 7) * 4 + ((bx >> 3) & 3);   // XCD-spread (b*H+h)
  int qb = 31 - (bx >> 5);                   // heavy blocks dispatched first
  int q0 = qb * 64 + wid * 16;               // this warp's 16 q-rows
  int nsteps = qb + 1;

  const char* Kb = (const char*)(Kr + (size_t)bh * S * DK);  // row stride 128B
  const char* Vb = (const char*)(Vt + (size_t)bh * DK * S);  // row stride 4096B
  const __bf16* Qh = Qr + (size_t)bh * S * DK;

  int o_lo = wid * 1024 + lane * 16;
#define STAGE(sel, kv0)                                                        \
  {                                                                            \
    char* kdst = smem + (sel) * 16384;                                         \
    _Pragma("unroll")                                                          \
    for (int i = 0; i < 2; ++i) {                                              \
      int o = o_lo + i * 4096;                                                 \
      int row = o >> 7;                                                        \
      int colp = (o & 127) ^ ((row & 7) << 4);                                 \
      gload16(Kb + (((size_t)((kv0) + row)) << 7) + colp,                      \
              kdst + wid * 1024 + i * 4096);                                   \
      gload16(Vb + ((size_t)row * S + (kv0)) * 2 + colp,                       \
              kdst + 8192 + wid * 1024 + i * 4096);                            \
    }                                                                          \
  }

  bf16x8 bq[2];
#pragma unroll
  for (int kc = 0; kc < 2; ++kc)
    bq[kc] = *(const bf16x8*)(Qh + (size_t)(q0 + lr) * DK + kc * 32 + lg * 8);

  int swz = (lr & 7) << 4;
  int oK0 = lr * 128 + ((lg * 16) ^ swz);
  int oK1 = lr * 128 + ((64 + lg * 16) ^ swz);
  int oV0 = lr * 128 + ((lg * 32) ^ swz);
  int oV1 = lr * 128 + ((16 + lg * 32) ^ swz);

  f32x4 o[4];
  float m2 = -3e38f, l2 = 0.f;
#pragma unroll
  for (int dt = 0; dt < 4; ++dt) o[dt] = (f32x4){0, 0, 0, 0};

  STAGE(0, 0);
  __syncthreads();

  for (int j = 0; j < nsteps; ++j) {
    int sel = j & 1;
    if (j + 1 < nsteps) STAGE(sel ^ 1, (j + 1) * 64);
    const char* kbuf = smem + sel * 16384;
    const char* vbuf = kbuf + 8192;
    int kv0 = j * 64;

    f32x4 sc[4];
#pragma unroll
    for (int kt = 0; kt < 4; ++kt) {
      bf16x8 ka0 = *(const bf16x8*)(kbuf + oK0 + kt * 2048);
      bf16x8 ka1 = *(const bf16x8*)(kbuf + oK1 + kt * 2048);
      f32x4 s = (f32x4){0, 0, 0, 0};
      s = __builtin_amdgcn_mfma_f32_16x16x32_bf16(ka0, bq[0], s, 0, 0, 0);
      s = __builtin_amdgcn_mfma_f32_16x16x32_bf16(ka1, bq[1], s, 0, 0, 0);
      sc[kt] = s;
    }

    if (j == qb) {
#pragma unroll
      for (int kt = 0; kt < 4; ++kt)
#pragma unroll
        for (int i = 0; i < 4; ++i)
          if (kv0 + kt * 16 + lg * 4 + i > q0 + lr)
            sc[kt][i] = -3e38f;
    }

    float tm = fmaxf(
        fmaxf(fmaxf(fmaxf(sc[0][0], sc[0][1]), fmaxf(sc[0][2], sc[0][3])),
              fmaxf(fmaxf(sc[1][0], sc[1][1]), fmaxf(sc[1][2], sc[1][3]))),
        fmaxf(fmaxf(fmaxf(sc[2][0], sc[2][1]), fmaxf(sc[2][2], sc[2][3])),
              fmaxf(fmaxf(sc[3][0], sc[3][1]), fmaxf(sc[3][2], sc[3][3]))));
    tm = fmaxf(tm, __shfl_xor(tm, 16));
    tm = fmaxf(tm, __shfl_xor(tm, 32));
    if (__any(tm > m2 + 8.0f)) {
      float mn = fmaxf(m2, tm);
      float f = fast_exp2(m2 - mn);
      m2 = mn;
      l2 *= f;
#pragma unroll
      for (int dt = 0; dt < 4; ++dt) o[dt] *= f;
    }
    float p[16];
#pragma unroll
    for (int kt = 0; kt < 4; ++kt)
#pragma unroll
      for (int i = 0; i < 4; ++i)
        p[kt * 4 + i] = fast_exp2(sc[kt][i] - m2);
    float sum = (((p[0] + p[1]) + (p[2] + p[3])) + ((p[4] + p[5]) + (p[6] + p[7]))) +
                (((p[8] + p[9]) + (p[10] + p[11])) + ((p[12] + p[13]) + (p[14] + p[15])));
    sum += __shfl_xor(sum, 16);
    sum += __shfl_xor(sum, 32);
    l2 += sum;
    bf16x8 pb[2];
#pragma unroll
    for (int kc = 0; kc < 2; ++kc) {
      bf16x8 pv;
#pragma unroll
      for (int a = 0; a < 2; ++a)
#pragma unroll
        for (int r = 0; r < 4; ++r)
          pv[a * 4 + r] = (__bf16)p[(2 * kc + a) * 4 + r];
      pb[kc] = pv;
    }

#pragma unroll
    for (int dt = 0; dt < 4; ++dt) {
      bf16x8 v0 = *(const bf16x8*)(vbuf + oV0 + dt * 2048);
      bf16x8 v1 = *(const bf16x8*)(vbuf + oV1 + dt * 2048);
      o[dt] = __builtin_amdgcn_mfma_f32_16x16x32_bf16(v0, pb[0], o[dt], 0, 0, 0);
      o[dt] = __builtin_amdgcn_mfma_f32_16x16x32_bf16(v1, pb[1], o[dt], 0, 0, 0);
    }
    __syncthreads();
  }
#undef STAGE

  int b = bh >> 4, h = bh & 15;
  float inv = 1.f / l2;
  int s = q0 + lr;
#pragma unroll
  for (int dt = 0; dt < 4; ++dt) {
    bf16x4 w;
#pragma unroll
    for (int i = 0; i < 4; ++i) w[i] = (__bf16)(o[dt][i] * inv);
    *(bf16x4*)&AO[(((size_t)(b * S + s)) * H + h) * DK + dt * 16 + lg * 4] = w;
  }
}

extern "C" void kernel_launch(void* const* d_in, const int* in_sizes, int n_in,
                              void* d_out, int out_size, void* d_ws, size_t ws_size,
                              hipStream_t stream) {
  const float* k_in = (const float*)d_in[0];
  const float* q_in = (const float*)d_in[1];
  const float* v_in = (const float*)d_in[2];
  const float* sinp = (const float*)d_in[4];
  const float* cosp = (const float*)d_in[5];
  const float* Wk = (const float*)d_in[6];
  const float* bk = (const float*)d_in[7];
  const float* Wq = (const float*)d_in[8];
  const float* bq = (const float*)d_in[9];
  const float* Wv = (const float*)d_in[10];
  const float* bv = (const float*)d_in[11];
  const float* Wo = (const float*)d_in[12];
  const float* bo = (const float*)d_in[13];
  float* out = (float*)d_out;

  __bf16* ws   = (__bf16*)d_ws;
  __bf16* Wall = ws;                   // [Wq|Wk|Wv|Wo] bf16
  __bf16* Qr   = ws + 4 * WE;          // (b,h,s,dk), pre-scaled
  __bf16* Kr   = Qr + NE;
  __bf16* Vt   = Kr + NE;              // (b,h,dk,s) perm64'd inner
  __bf16* AO   = Vt + NE;              // (b,s,h,dk)

  dim3 blk(256);
  cvt_w<<<dim3(512, 4), blk, 0, stream>>>(Wq, Wk, Wv, Wo, Wall);
  proj_kernel<<<768, blk, 0, stream>>>(q_in, k_in, v_in, Wall, bq, bk, bv,
                                       sinp, cosp, Qr, Kr, Vt);
  attn_kernel<<<1024, blk, 0, stream>>>(Qr, Kr, Vt, AO);
  outproj_kernel<<<512, blk, 0, stream>>>(AO, Wall + 3 * WE, bo, out);
}

// Round 10
// 107.317 us; speedup vs baseline: 1.2359x; 1.2359x over previous
//
#include <hip/hip_runtime.h>
#include <hip/hip_bf16.h>

typedef __bf16 bf16x8 __attribute__((ext_vector_type(8)));
typedef __bf16 bf16x4 __attribute__((ext_vector_type(4)));
typedef float  f32x4  __attribute__((ext_vector_type(4)));

static constexpr int B = 2, S = 2048, D = 1024, H = 16, DK = 64;
static constexpr int M = B * S;          // 4096
static constexpr int NE = M * D;         // 4194304
static constexpr int WE = D * D;         // 1048576

__device__ inline float fast_exp2(float x) { return __builtin_amdgcn_exp2f(x); }

__device__ inline void gload16(const void* g, void* l) {
  __builtin_amdgcn_global_load_lds(
      (const __attribute__((address_space(1))) void*)g,
      (__attribute__((address_space(3))) void*)l, 16, 0, 0);
}

// zero-shuffle V permutation: store kv-inner i (i=32kc+16a+4lg+r) at lg*16+kc*8+a*4+r
__device__ inline int perm64(int i) {
  return (((i >> 2) & 3) << 4) | (((i >> 5) & 1) << 3) | (((i >> 4) & 1) << 2) | (i & 3);
}

// ---------------- f32 -> bf16 conversion: weights only ---------------------
__global__ __launch_bounds__(256) void cvt_w(
    const float* __restrict__ Wq, const float* __restrict__ Wk,
    const float* __restrict__ Wv, const float* __restrict__ Wo,
    __bf16* __restrict__ Wall)
{
  int z = blockIdx.y;
  const float* src = (z == 0) ? Wq : (z == 1) ? Wk : (z == 2) ? Wv : Wo;
  __bf16* dst = Wall + (size_t)z * WE;
  int n4 = WE / 4;
  int i = blockIdx.x * blockDim.x + threadIdx.x;
  int stride = gridDim.x * blockDim.x;
  for (; i < n4; i += stride) {
    float4 f = reinterpret_cast<const float4*>(src)[i];
    bf16x4 o;
    o[0] = (__bf16)f.x; o[1] = (__bf16)f.y; o[2] = (__bf16)f.z; o[3] = (__bf16)f.w;
    reinterpret_cast<bf16x4*>(dst)[i] = o;
  }
}

// ---------------- fused QKV projection, BK=64, swizzled LDS ----------------
// Swapped operands: acc = mfma(W-frag, X-frag). W via global_load_lds with
// pre-swizzled source (rule #21); X via coalesced f32 load + in-reg cvt +
// swizzled ds_write_b128. Grid (m-tile fastest) keeps per-XCD X set L2-sized.
// Q pre-scaled by 0.125*log2(e); V stored transposed with perm64'd s-inner.
__global__ __launch_bounds__(256, 4) void proj_kernel(
    const float* __restrict__ Xq32, const float* __restrict__ Xk32,
    const float* __restrict__ Xv32, const __bf16* __restrict__ Wall,
    const float* __restrict__ bq_, const float* __restrict__ bk_,
    const float* __restrict__ bv_,
    const float* __restrict__ sinp, const float* __restrict__ cosp,
    __bf16* __restrict__ Qr, __bf16* __restrict__ Kr, __bf16* __restrict__ Vt)
{
  __shared__ __align__(16) __bf16 Ws[128 * 64];   // 16KB, swizzled rows (128B)
  __shared__ __align__(16) __bf16 Xs[128 * 64];   // 16KB, swizzled rows
  int tid = threadIdx.x;
  int lane = tid & 63, wid = tid >> 6;
  int lr = lane & 15, lg = lane >> 4;
  int wr = wid >> 1, wc = wid & 1;
  int m0 = blockIdx.x * 128;            // fastest dim -> XCD round-robin on m
  int by = blockIdx.y;                  // 0..23
  int z  = by >> 3;                     // 0:Q 1:K 2:V
  const float*  X32  = (z == 0) ? Xq32 : (z == 1) ? Xk32 : Xv32;
  const __bf16* Bw   = Wall + (size_t)by * 128 * 1024;
  const float*  bias = (z == 0) ? bq_ : (z == 1) ? bk_ : bv_;

  // W staging: 4 chunks of 4KB; row = c*32 + (tid>>3); pre-swizzled source col
  int wrow = tid >> 3;                  // 0..31
  int wcol = 8 * ((tid & 7) ^ ((tid >> 3) & 7));   // swizzle-inverse source col
  char* wsbase = (char*)Ws + wid * 1024;

  // X staging: 4 passes; row = p*32 + (tid>>3); 2 f32x4 -> bf16x8 -> 1 b128
  int xrow = tid >> 3;
  int xcolf = (tid & 7) * 8;            // f32 col within BK=64
  int xwb = ((tid & 7) * 16) ^ (((tid >> 3) & 7) << 4);  // swizzled write byte

  f32x4 acc[4][4];
#pragma unroll
  for (int i = 0; i < 4; ++i)
#pragma unroll
    for (int j = 0; j < 4; ++j) acc[i][j] = (f32x4){0, 0, 0, 0};

  // frag read offsets (swizzled): row*128 + ((h*64 + lg*16) ^ ((lr&7)<<4))
  int fsw = (lr & 7) << 4;
  int foff0 = (lg * 16) ^ fsw;          // h=0
  int foff1 = (64 + lg * 16) ^ fsw;     // h=1

  // prologue: X prefetch for k0=0 (cvt at load time -> 4 bf16x8 = 16 VGPR)
  bf16x8 xb[4];
#pragma unroll
  for (int p = 0; p < 4; ++p) {
    const float* xp = X32 + (size_t)(m0 + p * 32 + xrow) * 1024 + xcolf;
    f32x4 a = *(const f32x4*)(xp);
    f32x4 b = *(const f32x4*)(xp + 4);
    bf16x8 v;
#pragma unroll
    for (int e = 0; e < 4; ++e) { v[e] = (__bf16)a[e]; v[4 + e] = (__bf16)b[e]; }
    xb[p] = v;
  }

  for (int k0 = 0; k0 < 1024; k0 += 64) {
    // W stage (4 x gload16, pre-swizzled source)
#pragma unroll
    for (int c = 0; c < 4; ++c)
      gload16(Bw + (size_t)(c * 32 + wrow) * 1024 + k0 + wcol,
              wsbase + c * 4096);
    // X stage: write prefetched bf16x8 (swizzled)
#pragma unroll
    for (int p = 0; p < 4; ++p)
      *(bf16x8*)((char*)Xs + (p * 32 + xrow) * 128 + xwb) = xb[p];
    __syncthreads();
    // prefetch next X (latency hides under MFMA)
    if (k0 + 64 < 1024) {
#pragma unroll
      for (int p = 0; p < 4; ++p) {
        const float* xp = X32 + (size_t)(m0 + p * 32 + xrow) * 1024 + k0 + 64 + xcolf;
        f32x4 a = *(const f32x4*)(xp);
        f32x4 b = *(const f32x4*)(xp + 4);
        bf16x8 v;
#pragma unroll
        for (int e = 0; e < 4; ++e) { v[e] = (__bf16)a[e]; v[4 + e] = (__bf16)b[e]; }
        xb[p] = v;
      }
    }
    // compute: two K-halves of 32, 16 MFMA each
#pragma unroll
    for (int h = 0; h < 2; ++h) {
      int fo = h ? foff1 : foff0;
      bf16x8 af[4], bfr[4];
#pragma unroll
      for (int mi = 0; mi < 4; ++mi)
        af[mi] = *(const bf16x8*)((char*)Ws + (wr * 64 + mi * 16 + lr) * 128 + fo);
#pragma unroll
      for (int ni = 0; ni < 4; ++ni)
        bfr[ni] = *(const bf16x8*)((char*)Xs + (wc * 64 + ni * 16 + lr) * 128 + fo);
#pragma unroll
      for (int mi = 0; mi < 4; ++mi)
#pragma unroll
        for (int ni = 0; ni < 4; ++ni)
          acc[mi][ni] = __builtin_amdgcn_mfma_f32_16x16x32_bf16(af[mi], bfr[ni], acc[mi][ni], 0, 0, 0);
    }
    __syncthreads();
  }

  // epilogue: D row = dkf = by*128 + wr*64 + mi*16 + lg*4 + i ; D col = s
#pragma unroll
  for (int mi = 0; mi < 4; ++mi) {
    int dkf0 = by * 128 + wr * 64 + mi * 16 + lg * 4;
    int col0 = dkf0 & 1023;
    int h = col0 >> 6, dk0 = col0 & 63, t0 = dk0 >> 1;
    float4 bv4 = *reinterpret_cast<const float4*>(&bias[col0]);
#pragma unroll
    for (int ni = 0; ni < 4; ++ni) {
      int r = m0 + wc * 64 + ni * 16 + lr;
      int s = r & (S - 1), bb = r >> 11;
      float v0 = acc[mi][ni][0] + bv4.x;
      float v1 = acc[mi][ni][1] + bv4.y;
      float v2 = acc[mi][ni][2] + bv4.z;
      float v3 = acc[mi][ni][3] + bv4.w;
      if (z < 2) {
        float2 sn = *reinterpret_cast<const float2*>(&sinp[s * 32 + t0]);
        float2 cs = *reinterpret_cast<const float2*>(&cosp[s * 32 + t0]);
        float e0 = v0 * cs.x - v1 * sn.x, o0 = v0 * sn.x + v1 * cs.x;
        float e1 = v2 * cs.y - v3 * sn.y, o1 = v2 * sn.y + v3 * cs.y;
        if (z == 0) {
          e0 *= 0.18033688011112042f; o0 *= 0.18033688011112042f;  // 0.125*log2(e)
          e1 *= 0.18033688011112042f; o1 *= 0.18033688011112042f;
        }
        bf16x4 w;
        w[0] = (__bf16)e0; w[1] = (__bf16)o0; w[2] = (__bf16)e1; w[3] = (__bf16)o1;
        __bf16* dst = (z == 0) ? Qr : Kr;
        *(bf16x4*)&dst[((size_t)(bb * H + h) * S + s) * DK + dk0] = w;
      } else {
        int sp = (s & ~63) | perm64(s & 63);
        size_t base = ((size_t)(bb * H + h) * DK + dk0) * S + sp;
        Vt[base]         = (__bf16)v0;
        Vt[base + S]     = (__bf16)v1;
        Vt[base + 2 * S] = (__bf16)v2;
        Vt[base + 3 * S] = (__bf16)v3;
      }
    }
  }
}

// ---------------- output projection: 64x128 tiles, 2 blocks/CU -------------
__global__ __launch_bounds__(256) void outproj_kernel(
    const __bf16* __restrict__ AO, const __bf16* __restrict__ Wo,
    const float* __restrict__ bo_, float* __restrict__ out)
{
  __shared__ __align__(16) __bf16 As[64 * 32];    // AO tile (4KB)
  __shared__ __align__(16) __bf16 Bs[128 * 32];   // Wo tile (8KB)
  int tid = threadIdx.x;
  int lane = tid & 63, wid = tid >> 6;
  int lr = lane & 15, lg = lane >> 4;
  int wr = wid >> 1, wc = wid & 1;
  int m0 = blockIdx.x * 64;             // fastest dim -> XCD round-robin on m
  int n0 = blockIdx.y * 128;

  int arow = tid >> 2;                  // 0..63
  int acol = (tid & 3) * 8;
  int brow = tid >> 2;
  int bcol = (tid & 3) * 8;
  char* asw = (char*)As + wid * 1024;
  char* bsw = (char*)Bs + wid * 1024;

  f32x4 acc[4][2];
#pragma unroll
  for (int i = 0; i < 4; ++i)
#pragma unroll
    for (int j = 0; j < 2; ++j) acc[i][j] = (f32x4){0, 0, 0, 0};

  for (int k0 = 0; k0 < 1024; k0 += 32) {
    gload16(AO + (size_t)(m0 + arow) * 1024 + k0 + acol, asw);
    gload16(Wo + (size_t)(n0 + brow) * 1024 + k0 + bcol, bsw);
    gload16(Wo + (size_t)(n0 + brow + 64) * 1024 + k0 + bcol, bsw + 4096);
    __syncthreads();
    bf16x8 wf[4], aof[2];
#pragma unroll
    for (int mi = 0; mi < 4; ++mi)
      wf[mi]  = *reinterpret_cast<const bf16x8*>(&Bs[(wr*64 + mi*16 + lr)*32 + lg*8]);
#pragma unroll
    for (int ni = 0; ni < 2; ++ni)
      aof[ni] = *reinterpret_cast<const bf16x8*>(&As[(wc*32 + ni*16 + lr)*32 + lg*8]);
#pragma unroll
    for (int mi = 0; mi < 4; ++mi)
#pragma unroll
      for (int ni = 0; ni < 2; ++ni)
        acc[mi][ni] = __builtin_amdgcn_mfma_f32_16x16x32_bf16(wf[mi], aof[ni], acc[mi][ni], 0, 0, 0);
    __syncthreads();
  }

#pragma unroll
  for (int mi = 0; mi < 4; ++mi) {
    int c0 = n0 + wr * 64 + mi * 16 + lg * 4;
    float4 bv4 = *reinterpret_cast<const float4*>(&bo_[c0]);
#pragma unroll
    for (int ni = 0; ni < 2; ++ni) {
      int r = m0 + wc * 32 + ni * 16 + lr;
      float4 w;
      w.x = acc[mi][ni][0] + bv4.x;
      w.y = acc[mi][ni][1] + bv4.y;
      w.z = acc[mi][ni][2] + bv4.z;
      w.w = acc[mi][ni][3] + bv4.w;
      *reinterpret_cast<float4*>(&out[(size_t)r * 1024 + c0]) = w;
    }
  }
}

// ---------------- flash attention: 4-warp block, LDS-shared K/V ------------
__global__ __launch_bounds__(256, 4) void attn_kernel(
    const __bf16* __restrict__ Qr, const __bf16* __restrict__ Kr,
    const __bf16* __restrict__ Vt, __bf16* __restrict__ AO)
{
  __shared__ __align__(16) char smem[32768];   // [2][ K 8KB | V 8KB ]
  int tid = threadIdx.x;
  int lane = tid & 63, wid = tid >> 6;
  int lr = lane & 15, lg = lane >> 4;
  int bx = blockIdx.x;
  int bh = (bx & 7) * 4 + ((bx >> 3) & 3);   // XCD-spread (b*H+h)
  int qb = 31 - (bx >> 5);                   // heavy blocks dispatched first
  int q0 = qb * 64 + wid * 16;               // this warp's 16 q-rows
  int nsteps = qb + 1;

  const char* Kb = (const char*)(Kr + (size_t)bh * S * DK);  // row stride 128B
  const char* Vb = (const char*)(Vt + (size_t)bh * DK * S);  // row stride 4096B
  const __bf16* Qh = Qr + (size_t)bh * S * DK;

  int o_lo = wid * 1024 + lane * 16;
#define STAGE(sel, kv0)                                                        \
  {                                                                            \
    char* kdst = smem + (sel) * 16384;                                         \
    _Pragma("unroll")                                                          \
    for (int i = 0; i < 2; ++i) {                                              \
      int o = o_lo + i * 4096;                                                 \
      int row = o >> 7;                                                        \
      int colp = (o & 127) ^ ((row & 7) << 4);                                 \
      gload16(Kb + (((size_t)((kv0) + row)) << 7) + colp,                      \
              kdst + wid * 1024 + i * 4096);                                   \
      gload16(Vb + ((size_t)row * S + (kv0)) * 2 + colp,                       \
              kdst + 8192 + wid * 1024 + i * 4096);                            \
    }                                                                          \
  }

  bf16x8 bq[2];
#pragma unroll
  for (int kc = 0; kc < 2; ++kc)
    bq[kc] = *(const bf16x8*)(Qh + (size_t)(q0 + lr) * DK + kc * 32 + lg * 8);

  int swz = (lr & 7) << 4;
  int oK0 = lr * 128 + ((lg * 16) ^ swz);
  int oK1 = lr * 128 + ((64 + lg * 16) ^ swz);
  int oV0 = lr * 128 + ((lg * 32) ^ swz);
  int oV1 = lr * 128 + ((16 + lg * 32) ^ swz);

  f32x4 o[4];
  float m2 = -3e38f, l2 = 0.f;
#pragma unroll
  for (int dt = 0; dt < 4; ++dt) o[dt] = (f32x4){0, 0, 0, 0};

  STAGE(0, 0);
  __syncthreads();

  for (int j = 0; j < nsteps; ++j) {
    int sel = j & 1;
    if (j + 1 < nsteps) STAGE(sel ^ 1, (j + 1) * 64);
    const char* kbuf = smem + sel * 16384;
    const char* vbuf = kbuf + 8192;
    int kv0 = j * 64;

    f32x4 sc[4];
#pragma unroll
    for (int kt = 0; kt < 4; ++kt) {
      bf16x8 ka0 = *(const bf16x8*)(kbuf + oK0 + kt * 2048);
      bf16x8 ka1 = *(const bf16x8*)(kbuf + oK1 + kt * 2048);
      f32x4 s = (f32x4){0, 0, 0, 0};
      s = __builtin_amdgcn_mfma_f32_16x16x32_bf16(ka0, bq[0], s, 0, 0, 0);
      s = __builtin_amdgcn_mfma_f32_16x16x32_bf16(ka1, bq[1], s, 0, 0, 0);
      sc[kt] = s;
    }

    if (j == qb) {
#pragma unroll
      for (int kt = 0; kt < 4; ++kt)
#pragma unroll
        for (int i = 0; i < 4; ++i)
          if (kv0 + kt * 16 + lg * 4 + i > q0 + lr)
            sc[kt][i] = -3e38f;
    }

    float tm = fmaxf(
        fmaxf(fmaxf(fmaxf(sc[0][0], sc[0][1]), fmaxf(sc[0][2], sc[0][3])),
              fmaxf(fmaxf(sc[1][0], sc[1][1]), fmaxf(sc[1][2], sc[1][3]))),
        fmaxf(fmaxf(fmaxf(sc[2][0], sc[2][1]), fmaxf(sc[2][2], sc[2][3])),
              fmaxf(fmaxf(sc[3][0], sc[3][1]), fmaxf(sc[3][2], sc[3][3]))));
    tm = fmaxf(tm, __shfl_xor(tm, 16));
    tm = fmaxf(tm, __shfl_xor(tm, 32));
    if (__any(tm > m2 + 8.0f)) {
      float mn = fmaxf(m2, tm);
      float f = fast_exp2(m2 - mn);
      m2 = mn;
      l2 *= f;
#pragma unroll
      for (int dt = 0; dt < 4; ++dt) o[dt] *= f;
    }
    float p[16];
#pragma unroll
    for (int kt = 0; kt < 4; ++kt)
#pragma unroll
      for (int i = 0; i < 4; ++i)
        p[kt * 4 + i] = fast_exp2(sc[kt][i] - m2);
    float sum = (((p[0] + p[1]) + (p[2] + p[3])) + ((p[4] + p[5]) + (p[6] + p[7]))) +
                (((p[8] + p[9]) + (p[10] + p[11])) + ((p[12] + p[13]) + (p[14] + p[15])));
    sum += __shfl_xor(sum, 16);
    sum += __shfl_xor(sum, 32);
    l2 += sum;
    bf16x8 pb[2];
#pragma unroll
    for (int kc = 0; kc < 2; ++kc) {
      bf16x8 pv;
#pragma unroll
      for (int a = 0; a < 2; ++a)
#pragma unroll
        for (int r = 0; r < 4; ++r)
          pv[a * 4 + r] = (__bf16)p[(2 * kc + a) * 4 + r];
      pb[kc] = pv;
    }

#pragma unroll
    for (int dt = 0; dt < 4; ++dt) {
      bf16x8 v0 = *(const bf16x8*)(vbuf + oV0 + dt * 2048);
      bf16x8 v1 = *(const bf16x8*)(vbuf + oV1 + dt * 2048);
      o[dt] = __builtin_amdgcn_mfma_f32_16x16x32_bf16(v0, pb[0], o[dt], 0, 0, 0);
      o[dt] = __builtin_amdgcn_mfma_f32_16x16x32_bf16(v1, pb[1], o[dt], 0, 0, 0);
    }
    __syncthreads();
  }
#undef STAGE

  int b = bh >> 4, h = bh & 15;
  float inv = 1.f / l2;
  int s = q0 + lr;
#pragma unroll
  for (int dt = 0; dt < 4; ++dt) {
    bf16x4 w;
#pragma unroll
    for (int i = 0; i < 4; ++i) w[i] = (__bf16)(o[dt][i] * inv);
    *(bf16x4*)&AO[(((size_t)(b * S + s)) * H + h) * DK + dt * 16 + lg * 4] = w;
  }
}

extern "C" void kernel_launch(void* const* d_in, const int* in_sizes, int n_in,
                              void* d_out, int out_size, void* d_ws, size_t ws_size,
                              hipStream_t stream) {
  const float* k_in = (const float*)d_in[0];
  const float* q_in = (const float*)d_in[1];
  const float* v_in = (const float*)d_in[2];
  const float* sinp = (const float*)d_in[4];
  const float* cosp = (const float*)d_in[5];
  const float* Wk = (const float*)d_in[6];
  const float* bk = (const float*)d_in[7];
  const float* Wq = (const float*)d_in[8];
  const float* bq = (const float*)d_in[9];
  const float* Wv = (const float*)d_in[10];
  const float* bv = (const float*)d_in[11];
  const float* Wo = (const float*)d_in[12];
  const float* bo = (const float*)d_in[13];
  float* out = (float*)d_out;

  __bf16* ws   = (__bf16*)d_ws;
  __bf16* Wall = ws;                   // [Wq|Wk|Wv|Wo] bf16
  __bf16* Qr   = ws + 4 * WE;          // (b,h,s,dk), pre-scaled
  __bf16* Kr   = Qr + NE;
  __bf16* Vt   = Kr + NE;              // (b,h,dk,s) perm64'd inner
  __bf16* AO   = Vt + NE;              // (b,s,h,dk)

  dim3 blk(256);
  cvt_w<<<dim3(512, 4), blk, 0, stream>>>(Wq, Wk, Wv, Wo, Wall);
  proj_kernel<<<dim3(32, 24), blk, 0, stream>>>(q_in, k_in, v_in, Wall, bq, bk, bv,
                                                sinp, cosp, Qr, Kr, Vt);
  attn_kernel<<<1024, blk, 0, stream>>>(Qr, Kr, Vt, AO);
  outproj_kernel<<<dim3(64, 8), blk, 0, stream>>>(AO, Wall + 3 * WE, bo, out);
}